// Round 1
// baseline (7602.007 us; speedup 1.0000x reference)
//
#include <hip/hip_runtime.h>
#include <cstddef>

// ---------------------------------------------------------------------------
// Encoder: 3 blocks of [stride-2 conv -> BN(active)+ELU -> stride-1 conv ->
// BN(active)+ELU] on dense grids (masks are ~100% dense after first pool),
// then masked global mean pool + two 512x512 linear heads.
// Round 1:全 fp32, correctness-first. conv = implicit GEMM on vector ALU,
// weights kept wave-uniform (readfirstlane'd chunk) so they become s_loads.
// ---------------------------------------------------------------------------

#define EPSV 1e-5f

// ---------------- mask pooling ----------------
__global__ __launch_bounds__(256) void pool0_kernel(const int* __restrict__ mask,
                                                    float* __restrict__ mout) {
    int voxel = blockIdx.x * 256 + threadIdx.x;          // 4 * 64^3
    int wo = voxel & 63, ho = (voxel >> 6) & 63, dd = (voxel >> 12) & 63, b = voxel >> 18;
    int any = 0;
#pragma unroll
    for (int dz = 0; dz < 2; ++dz)
#pragma unroll
        for (int hy = 0; hy < 2; ++hy)
#pragma unroll
            for (int wx = 0; wx < 2; ++wx) {
                size_t idx = ((size_t)((b * 128 + 2 * dd + dz) * 128 + 2 * ho + hy)) * 128
                             + 2 * wo + wx;
                any |= mask[idx];
            }
    mout[voxel] = any ? 1.f : 0.f;
}

__global__ __launch_bounds__(256) void poolf_kernel(const float* __restrict__ min_,
                                                    float* __restrict__ mout,
                                                    int Nout, int lnout) {
    int voxel = blockIdx.x * 256 + threadIdx.x;
    int Nin = Nout * 2;
    int wo = voxel & (Nout - 1);
    int ho = (voxel >> lnout) & (Nout - 1);
    int dd = (voxel >> (2 * lnout)) & (Nout - 1);
    int b = voxel >> (3 * lnout);
    float mx = 0.f;
#pragma unroll
    for (int dz = 0; dz < 2; ++dz)
#pragma unroll
        for (int hy = 0; hy < 2; ++hy)
#pragma unroll
            for (int wx = 0; wx < 2; ++wx) {
                size_t idx = ((size_t)((b * Nin + 2 * dd + dz) * Nin + 2 * ho + hy)) * Nin
                             + 2 * wo + wx;
                mx = fmaxf(mx, min_[idx]);
            }
    mout[voxel] = mx;
}

// ---------------- mask counts (total + optional per-batch) ----------------
__global__ __launch_bounds__(256) void mask_count_kernel(const float* __restrict__ m,
                                                         int nper, int blocks_per_batch,
                                                         float* __restrict__ cnt_total,
                                                         float* __restrict__ cnt_batch) {
    int batch = blockIdx.x / blocks_per_batch;
    int off = (blockIdx.x % blocks_per_batch) * 1024;
    float s = 0.f;
    for (int i = threadIdx.x; i < 1024; i += 256)
        s += m[(size_t)batch * nper + off + i];
    __shared__ float red[256];
    red[threadIdx.x] = s;
    __syncthreads();
    for (int st = 128; st > 0; st >>= 1) {
        if (threadIdx.x < st) red[threadIdx.x] += red[threadIdx.x + st];
        __syncthreads();
    }
    if (threadIdx.x == 0) {
        atomicAdd(cnt_total, red[0]);
        if (cnt_batch) atomicAdd(&cnt_batch[batch], red[0]);
    }
}

// ---------------- conv1a: Cin=1, Cout=16, stride 2, 128^3 -> 64^3 ----------
__global__ __launch_bounds__(256) void conv1a_kernel(const float* __restrict__ x,
                                                     const int* __restrict__ mask,
                                                     const float* __restrict__ w,
                                                     const float* __restrict__ m1,
                                                     float* __restrict__ out) {
    int voxel = blockIdx.x * 256 + threadIdx.x;  // 4 * 64^3
    int wo = voxel & 63, ho = (voxel >> 6) & 63, dd = (voxel >> 12) & 63, b = voxel >> 18;
    float acc[16];
#pragma unroll
    for (int i = 0; i < 16; ++i) acc[i] = 0.f;
    for (int kd = 0; kd < 3; ++kd) {
        int id = 2 * dd + kd - 1;
        if ((unsigned)id >= 128u) continue;
        for (int kh = 0; kh < 3; ++kh) {
            int ih = 2 * ho + kh - 1;
            if ((unsigned)ih >= 128u) continue;
            for (int kw = 0; kw < 3; ++kw) {
                int iw = 2 * wo + kw - 1;
                if ((unsigned)iw >= 128u) continue;
                size_t idx = ((size_t)((b * 128 + id) * 128 + ih)) * 128 + iw;
                float xv = x[idx] * (float)mask[idx];
                const float* wp = w + ((kd * 3 + kh) * 3 + kw) * 16;
#pragma unroll
                for (int co = 0; co < 16; ++co) acc[co] = fmaf(xv, wp[co], acc[co]);
            }
        }
    }
    float m = m1[voxel];
    float* op = out + (size_t)voxel * 16;
#pragma unroll
    for (int co = 0; co < 16; co += 4) {
        float4 v;
        v.x = acc[co] * m; v.y = acc[co + 1] * m; v.z = acc[co + 2] * m; v.w = acc[co + 3] * m;
        *(float4*)(op + co) = v;
    }
}

// ---------------- generic conv: thread = (voxel lane, wave-uniform cout chunk)
template <int CIN, int COUT, int CHUNK, int STRIDE>
__global__ __launch_bounds__(256) void conv3d_kernel(const float* __restrict__ in,
                                                     const float* __restrict__ w,
                                                     const float* __restrict__ mout,
                                                     float* __restrict__ out,
                                                     int Nin, int Nout, int lnout) {
    constexpr int NCHUNK = COUT / CHUNK;
    int gtid = blockIdx.x * 256 + threadIdx.x;
    int wave = gtid >> 6;
    int lane = gtid & 63;
    int chunk = wave % NCHUNK;
    chunk = __builtin_amdgcn_readfirstlane(chunk);  // force SGPR -> s_load weights
    int voxel = (wave / NCHUNK) * 64 + lane;
    int wo = voxel & (Nout - 1);
    int ho = (voxel >> lnout) & (Nout - 1);
    int dd = (voxel >> (2 * lnout)) & (Nout - 1);
    int b = voxel >> (3 * lnout);

    float acc[CHUNK];
#pragma unroll
    for (int i = 0; i < CHUNK; ++i) acc[i] = 0.f;

    const float* wbase = w + chunk * CHUNK;
    for (int kd = 0; kd < 3; ++kd) {
        int id = dd * STRIDE + kd - 1;
        if ((unsigned)id >= (unsigned)Nin) continue;
        for (int kh = 0; kh < 3; ++kh) {
            int ih = ho * STRIDE + kh - 1;
            if ((unsigned)ih >= (unsigned)Nin) continue;
            for (int kw = 0; kw < 3; ++kw) {
                int iw = wo * STRIDE + kw - 1;
                if ((unsigned)iw >= (unsigned)Nin) continue;
                const float* ip = in + ((size_t)(((b * Nin + id) * Nin + ih) * Nin + iw)) * CIN;
                const float* wp = wbase + ((kd * 3 + kh) * 3 + kw) * (CIN * COUT);
#pragma unroll 1
                for (int ci = 0; ci < CIN; ci += 4) {
                    float4 xv = *(const float4*)(ip + ci);
                    const float* wr = wp + ci * COUT;
#pragma unroll
                    for (int co = 0; co < CHUNK; ++co) acc[co] = fmaf(xv.x, wr[co], acc[co]);
#pragma unroll
                    for (int co = 0; co < CHUNK; ++co) acc[co] = fmaf(xv.y, wr[COUT + co], acc[co]);
#pragma unroll
                    for (int co = 0; co < CHUNK; ++co) acc[co] = fmaf(xv.z, wr[2 * COUT + co], acc[co]);
#pragma unroll
                    for (int co = 0; co < CHUNK; ++co) acc[co] = fmaf(xv.w, wr[3 * COUT + co], acc[co]);
                }
            }
        }
    }
    float m = mout[voxel];
    float* op = out + (size_t)voxel * COUT + chunk * CHUNK;
#pragma unroll
    for (int co = 0; co < CHUNK; co += 4) {
        float4 v;
        v.x = acc[co] * m; v.y = acc[co + 1] * m; v.z = acc[co + 2] * m; v.w = acc[co + 3] * m;
        *(float4*)(op + co) = v;
    }
}

// ---------------- BN stats: per-channel sum & sumsq over dense (masked) data
template <int C>
__global__ __launch_bounds__(256) void bn_stats_kernel(const float* __restrict__ x,
                                                       int nvox, float* __restrict__ stats) {
    if constexpr (C <= 256) {
        // stride and block base are multiples of C -> each thread owns one channel
        float s = 0.f, q = 0.f;
        long total = (long)nvox * C;
        long stride = (long)gridDim.x * 256;
        for (long i = (long)blockIdx.x * 256 + threadIdx.x; i < total; i += stride) {
            float v = x[i];
            s += v;
            q += v * v;
        }
        __shared__ float ls[256], lq[256];
        ls[threadIdx.x] = s;
        lq[threadIdx.x] = q;
        __syncthreads();
        for (int st = 128; st >= C; st >>= 1) {
            if (threadIdx.x < st) {
                ls[threadIdx.x] += ls[threadIdx.x + st];
                lq[threadIdx.x] += lq[threadIdx.x + st];
            }
            __syncthreads();
        }
        if (threadIdx.x < C) {
            atomicAdd(&stats[threadIdx.x], ls[threadIdx.x]);
            atomicAdd(&stats[C + threadIdx.x], lq[threadIdx.x]);
        }
    } else {  // C == 512: two channels per thread, per-voxel grid-stride
        int c0 = threadIdx.x, c1 = threadIdx.x + 256;
        float s0 = 0.f, q0 = 0.f, s1 = 0.f, q1 = 0.f;
        for (int v = blockIdx.x; v < nvox; v += gridDim.x) {
            float a = x[(size_t)v * C + c0];
            s0 += a; q0 += a * a;
            float b = x[(size_t)v * C + c1];
            s1 += b; q1 += b * b;
        }
        atomicAdd(&stats[c0], s0);
        atomicAdd(&stats[C + c0], q0);
        atomicAdd(&stats[c1], s1);
        atomicAdd(&stats[C + c1], q1);
    }
}

// ---------------- BN apply + ELU + mask ----------------
template <int C, int LOGC>
__global__ __launch_bounds__(256) void bn_apply_kernel(float* __restrict__ x,
                                                       const float* __restrict__ m,
                                                       const float* __restrict__ stats,
                                                       const float* __restrict__ cnt,
                                                       const float* __restrict__ gamma,
                                                       const float* __restrict__ beta,
                                                       int nvox) {
    float cn = *cnt;
    long total = (long)nvox * C;
    long stride = (long)gridDim.x * blockDim.x;
    for (long i = (long)blockIdx.x * blockDim.x + threadIdx.x; i < total; i += stride) {
        int c = (int)(i & (C - 1));
        long v = i >> LOGC;
        float mean = stats[c] / cn;
        float var = stats[C + c] / cn - mean * mean;
        float xh = (x[i] - mean) * rsqrtf(var + EPSV) * gamma[c] + beta[c];
        float e = xh > 0.f ? xh : expm1f(xh);
        x[i] = e * m[v];
    }
}

// ---------------- global masked mean pool (sums; divide in head) -----------
__global__ __launch_bounds__(256) void gpool_kernel(const float* __restrict__ h,
                                                    float* __restrict__ pooled) {
    int b = blockIdx.x >> 4;
    int v0 = (blockIdx.x & 15) << 8;
    float s0 = 0.f, s1 = 0.f;
    for (int v = 0; v < 256; ++v) {
        const float* p = h + ((size_t)(b * 4096 + v0 + v)) * 512;
        s0 += p[threadIdx.x];
        s1 += p[threadIdx.x + 256];
    }
    atomicAdd(&pooled[b * 512 + threadIdx.x], s0);
    atomicAdd(&pooled[b * 512 + threadIdx.x + 256], s1);
}

// ---------------- heads: mean = pooled@wm+bm, log_var = pooled@wv+bv -------
__global__ __launch_bounds__(256) void head_kernel(const float* __restrict__ pooled,
                                                   const float* __restrict__ cntb,
                                                   const float* __restrict__ wm,
                                                   const float* __restrict__ bm,
                                                   const float* __restrict__ wv,
                                                   const float* __restrict__ bv,
                                                   float* __restrict__ out) {
    int t = blockIdx.x * 256 + threadIdx.x;  // 4096
    int which = t >> 11;
    int b = (t >> 9) & 3;
    int j = t & 511;
    const float* W = which ? wv : wm;
    float bias = which ? bv[j] : bm[j];
    const float* p = pooled + b * 512;
    float s = 0.f;
    for (int c = 0; c < 512; ++c) s = fmaf(p[c], W[c * 512 + j], s);
    out[t] = s / cntb[b] + bias;
}

// ---------------------------------------------------------------------------
extern "C" void kernel_launch(void* const* d_in, const int* in_sizes, int n_in,
                              void* d_out, int out_size, void* d_ws, size_t ws_size,
                              hipStream_t stream) {
    const float* x   = (const float*)d_in[0];
    const int* mask  = (const int*)d_in[1];
    const float* w1a = (const float*)d_in[2];
    const float* g1a = (const float*)d_in[3];
    const float* b1a = (const float*)d_in[4];
    const float* w1b = (const float*)d_in[5];
    const float* g1b = (const float*)d_in[6];
    const float* b1b = (const float*)d_in[7];
    const float* w2a = (const float*)d_in[8];
    const float* g2a = (const float*)d_in[9];
    const float* b2a = (const float*)d_in[10];
    const float* w2b = (const float*)d_in[11];
    const float* g2b = (const float*)d_in[12];
    const float* b2b = (const float*)d_in[13];
    const float* w3a = (const float*)d_in[14];
    const float* g3a = (const float*)d_in[15];
    const float* b3a = (const float*)d_in[16];
    const float* w3b = (const float*)d_in[17];
    const float* g3b = (const float*)d_in[18];
    const float* b3b = (const float*)d_in[19];
    const float* wm  = (const float*)d_in[20];
    const float* bm  = (const float*)d_in[21];
    const float* wv  = (const float*)d_in[22];
    const float* bv  = (const float*)d_in[23];
    float* out = (float*)d_out;

    char* ws = (char*)d_ws;
    // Region reuse: A holds h1a then {h2a, h3a}; B holds h1b then {h2b, h3b}.
    float* A  = (float*)(ws + 0);            // 67,108,864 B
    float* Bb = (float*)(ws + 67108864);     // 67,108,864 B
    float* m1 = (float*)(ws + 134217728);    // 4 MB
    float* m2 = (float*)(ws + 138412032);    // 512 KB
    float* m3 = (float*)(ws + 138936320);    // 64 KB
    float* stats  = (float*)(ws + 139001856);  // 4 KB (reused per BN)
    float* counts = (float*)(ws + 139005952);  // 16 floats: [0]=cnt1 [1]=cnt2 [2]=cnt3 [4..7]=per-batch cnt3
    float* pooled = (float*)(ws + 139006016);  // 4x512 floats

    float* h1a = A;
    float* h1b = Bb;
    float* h2a = A;
    float* h2b = Bb;
    float* h3a = A + 8388608;   // byte offset 33,554,432
    float* h3b = Bb + 8388608;

    // zero counts + pooled in one shot (contiguous)
    hipMemsetAsync(counts, 0, (16 + 2048) * sizeof(float), stream);

    // masks + counts
    pool0_kernel<<<4096, 256, 0, stream>>>(mask, m1);
    poolf_kernel<<<512, 256, 0, stream>>>(m1, m2, 32, 5);
    poolf_kernel<<<64, 256, 0, stream>>>(m2, m3, 16, 4);
    mask_count_kernel<<<1024, 256, 0, stream>>>(m1, 262144, 256, counts + 0, nullptr);
    mask_count_kernel<<<128, 256, 0, stream>>>(m2, 32768, 32, counts + 1, nullptr);
    mask_count_kernel<<<16, 256, 0, stream>>>(m3, 4096, 4, counts + 2, counts + 4);

    // ---- block 1 ----
    conv1a_kernel<<<4096, 256, 0, stream>>>(x, mask, w1a, m1, h1a);
    hipMemsetAsync(stats, 0, 4096, stream);
    bn_stats_kernel<16><<<2048, 256, 0, stream>>>(h1a, 1048576, stats);
    bn_apply_kernel<16, 4><<<4096, 256, 0, stream>>>(h1a, m1, stats, counts + 0, g1a, b1a, 1048576);

    conv3d_kernel<16, 16, 16, 1><<<4096, 256, 0, stream>>>(h1a, w1b, m1, h1b, 64, 64, 6);
    hipMemsetAsync(stats, 0, 4096, stream);
    bn_stats_kernel<16><<<2048, 256, 0, stream>>>(h1b, 1048576, stats);
    bn_apply_kernel<16, 4><<<4096, 256, 0, stream>>>(h1b, m1, stats, counts + 0, g1b, b1b, 1048576);

    // ---- block 2 ----
    conv3d_kernel<16, 64, 32, 2><<<1024, 256, 0, stream>>>(h1b, w2a, m2, h2a, 64, 32, 5);
    hipMemsetAsync(stats, 0, 4096, stream);
    bn_stats_kernel<64><<<2048, 256, 0, stream>>>(h2a, 131072, stats);
    bn_apply_kernel<64, 6><<<2048, 256, 0, stream>>>(h2a, m2, stats, counts + 1, g2a, b2a, 131072);

    conv3d_kernel<64, 64, 32, 1><<<1024, 256, 0, stream>>>(h2a, w2b, m2, h2b, 32, 32, 5);
    hipMemsetAsync(stats, 0, 4096, stream);
    bn_stats_kernel<64><<<2048, 256, 0, stream>>>(h2b, 131072, stats);
    bn_apply_kernel<64, 6><<<2048, 256, 0, stream>>>(h2b, m2, stats, counts + 1, g2b, b2b, 131072);

    // ---- block 3 ----
    conv3d_kernel<64, 512, 32, 2><<<1024, 256, 0, stream>>>(h2b, w3a, m3, h3a, 32, 16, 4);
    hipMemsetAsync(stats, 0, 4096, stream);
    bn_stats_kernel<512><<<1024, 256, 0, stream>>>(h3a, 16384, stats);
    bn_apply_kernel<512, 9><<<2048, 256, 0, stream>>>(h3a, m3, stats, counts + 2, g3a, b3a, 16384);

    conv3d_kernel<512, 512, 32, 1><<<1024, 256, 0, stream>>>(h3a, w3b, m3, h3b, 16, 16, 4);
    hipMemsetAsync(stats, 0, 4096, stream);
    bn_stats_kernel<512><<<1024, 256, 0, stream>>>(h3b, 16384, stats);
    bn_apply_kernel<512, 9><<<2048, 256, 0, stream>>>(h3b, m3, stats, counts + 2, g3b, b3b, 16384);

    // ---- pool + heads ----
    gpool_kernel<<<64, 256, 0, stream>>>(h3b, pooled);
    head_kernel<<<16, 256, 0, stream>>>(pooled, counts + 4, wm, bm, wv, bv, out);
}

// Round 2
// 2753.110 us; speedup vs baseline: 2.7612x; 2.7612x over previous
//
#include <hip/hip_runtime.h>
#include <cstddef>

// ---------------------------------------------------------------------------
// Encoder, round 2: fp16 MFMA implicit-GEMM convs.
// Pipeline dtype: activations fp16 (h buffers), BN stats/apply in fp32 math,
// masks fp32, heads fp32. Weights pre-transposed to [tap][cout][cin] fp16.
// conv tile: M=64 voxels (4x4x4 cube), NTILE couts per block, halo in LDS.
// ---------------------------------------------------------------------------

#define EPSV 1e-5f

typedef _Float16 f16x4 __attribute__((ext_vector_type(4)));
typedef _Float16 f16x8 __attribute__((ext_vector_type(8)));
typedef float f32x4 __attribute__((ext_vector_type(4)));

// ---------------- mask pooling ----------------
__global__ __launch_bounds__(256) void pool0_kernel(const int* __restrict__ mask,
                                                    float* __restrict__ mout) {
    int voxel = blockIdx.x * 256 + threadIdx.x;          // 4 * 64^3
    int wo = voxel & 63, ho = (voxel >> 6) & 63, dd = (voxel >> 12) & 63, b = voxel >> 18;
    int any = 0;
#pragma unroll
    for (int dz = 0; dz < 2; ++dz)
#pragma unroll
        for (int hy = 0; hy < 2; ++hy)
#pragma unroll
            for (int wx = 0; wx < 2; ++wx) {
                size_t idx = ((size_t)((b * 128 + 2 * dd + dz) * 128 + 2 * ho + hy)) * 128
                             + 2 * wo + wx;
                any |= mask[idx];
            }
    mout[voxel] = any ? 1.f : 0.f;
}

__global__ __launch_bounds__(256) void poolf_kernel(const float* __restrict__ min_,
                                                    float* __restrict__ mout,
                                                    int Nout, int lnout) {
    int voxel = blockIdx.x * 256 + threadIdx.x;
    int Nin = Nout * 2;
    int wo = voxel & (Nout - 1);
    int ho = (voxel >> lnout) & (Nout - 1);
    int dd = (voxel >> (2 * lnout)) & (Nout - 1);
    int b = voxel >> (3 * lnout);
    float mx = 0.f;
#pragma unroll
    for (int dz = 0; dz < 2; ++dz)
#pragma unroll
        for (int hy = 0; hy < 2; ++hy)
#pragma unroll
            for (int wx = 0; wx < 2; ++wx) {
                size_t idx = ((size_t)((b * Nin + 2 * dd + dz) * Nin + 2 * ho + hy)) * Nin
                             + 2 * wo + wx;
                mx = fmaxf(mx, min_[idx]);
            }
    mout[voxel] = mx;
}

// ---------------- mask counts ----------------
__global__ __launch_bounds__(256) void mask_count_kernel(const float* __restrict__ m,
                                                         int nper, int blocks_per_batch,
                                                         float* __restrict__ cnt_total,
                                                         float* __restrict__ cnt_batch) {
    int batch = blockIdx.x / blocks_per_batch;
    int off = (blockIdx.x % blocks_per_batch) * 1024;
    float s = 0.f;
    for (int i = threadIdx.x; i < 1024; i += 256)
        s += m[(size_t)batch * nper + off + i];
    __shared__ float red[256];
    red[threadIdx.x] = s;
    __syncthreads();
    for (int st = 128; st > 0; st >>= 1) {
        if (threadIdx.x < st) red[threadIdx.x] += red[threadIdx.x + st];
        __syncthreads();
    }
    if (threadIdx.x == 0) {
        atomicAdd(cnt_total, red[0]);
        if (cnt_batch) atomicAdd(&cnt_batch[batch], red[0]);
    }
}

// ---------------- weight transform: [27][CIN][COUT] f32 -> [27][COUT][CIN] f16
__global__ __launch_bounds__(256) void wtrans_kernel(const float* __restrict__ w,
                                                     _Float16* __restrict__ o,
                                                     int CIN, int COUT, int total) {
    int i = blockIdx.x * 256 + threadIdx.x;
    if (i >= total) return;
    int co = i % COUT;
    int rest = i / COUT;
    int ci = rest % CIN;
    int t = rest / CIN;
    o[((size_t)(t * COUT + co)) * CIN + ci] = (_Float16)w[i];
}

// ---------------- conv1a: Cin=1, Cout=16, stride 2, 128^3 -> 64^3 (VALU) ----
__global__ __launch_bounds__(256) void conv1a_kernel(const float* __restrict__ x,
                                                     const int* __restrict__ mask,
                                                     const float* __restrict__ w,
                                                     const float* __restrict__ m1,
                                                     _Float16* __restrict__ out) {
    int voxel = blockIdx.x * 256 + threadIdx.x;  // 4 * 64^3
    int wo = voxel & 63, ho = (voxel >> 6) & 63, dd = (voxel >> 12) & 63, b = voxel >> 18;
    float acc[16];
#pragma unroll
    for (int i = 0; i < 16; ++i) acc[i] = 0.f;
    for (int kd = 0; kd < 3; ++kd) {
        int id = 2 * dd + kd - 1;
        if ((unsigned)id >= 128u) continue;
        for (int kh = 0; kh < 3; ++kh) {
            int ih = 2 * ho + kh - 1;
            if ((unsigned)ih >= 128u) continue;
            for (int kw = 0; kw < 3; ++kw) {
                int iw = 2 * wo + kw - 1;
                if ((unsigned)iw >= 128u) continue;
                size_t idx = ((size_t)((b * 128 + id) * 128 + ih)) * 128 + iw;
                float xv = x[idx] * (float)mask[idx];
                const float* wp = w + ((kd * 3 + kh) * 3 + kw) * 16;
#pragma unroll
                for (int co = 0; co < 16; ++co) acc[co] = fmaf(xv, wp[co], acc[co]);
            }
        }
    }
    float m = m1[voxel];
    _Float16* op = out + (size_t)voxel * 16;
#pragma unroll
    for (int co = 0; co < 16; ++co) op[co] = (_Float16)(acc[co] * m);
}

// ---------------- MFMA implicit-GEMM conv ----------------
// Block: 256 threads = 4 waves. Output tile: 64 voxels (4x4x4), NTILE couts.
// Wave w owns od-slice w (16 voxels) x all NTILE couts.
// K loop: cin chunks of KC (32 or 16) staged as halo slice in LDS, x 27 taps.
template <int CIN, int COUT, int NTILE, int STRIDE, int NIN, int NOUT>
__global__ __launch_bounds__(256) void mfma_conv_kernel(const _Float16* __restrict__ in,
                                                        const _Float16* __restrict__ wt,
                                                        const float* __restrict__ mout,
                                                        _Float16* __restrict__ out) {
    constexpr int KC = (CIN >= 32) ? 32 : 16;
    constexpr int NF = NTILE / 16;
    constexpr int HS = 3 * STRIDE + 3;     // halo extent: 6 (s1) or 9 (s2)
    constexpr int HV = HS * HS * HS;
    constexpr int PADH = (KC == 32) ? 40 : 20;   // halfs per halo voxel (padded)
    constexpr int TD = NOUT / 4;
    constexpr int NBLK = COUT / NTILE;

    __shared__ _Float16 lds[HV * PADH];

    int bid = blockIdx.x;
    int nblk = bid % NBLK;
    int mblk = bid / NBLK;
    int tw = mblk % TD;
    int th = (mblk / TD) % TD;
    int td = (mblk / (TD * TD)) % TD;
    int b  = mblk / (TD * TD * TD);
    int d0 = td * 4 * STRIDE - 1, h0 = th * 4 * STRIDE - 1, w0 = tw * 4 * STRIDE - 1;

    int lane = threadIdx.x & 63;
    int wv = threadIdx.x >> 6;       // wave id == od within tile
    int m = lane & 15;
    int quad = lane >> 4;

    // per-lane A base offset within halo (in voxels)
    int row_off = (wv * STRIDE) * HS * HS + ((m >> 2) * STRIDE) * HS + (m & 3) * STRIDE;
    // per-lane weight base
    const _Float16* wlane = wt + (size_t)(nblk * NTILE + m) * CIN + quad * (KC / 4);

    f32x4 acc[NF];
#pragma unroll
    for (int i = 0; i < NF; ++i) acc[i] = (f32x4){0.f, 0.f, 0.f, 0.f};

    for (int c0 = 0; c0 < CIN; c0 += KC) {
        __syncthreads();
        // ---- stage halo slice (HV voxels x KC channels) ----
        for (int hv = threadIdx.x; hv < HV; hv += 256) {
            int hw_ = hv % HS;
            int t_ = hv / HS;
            int hh = t_ % HS;
            int hd = t_ / HS;
            int d = d0 + hd, h = h0 + hh, w = w0 + hw_;
            bool ok = ((unsigned)d < (unsigned)NIN) & ((unsigned)h < (unsigned)NIN) &
                      ((unsigned)w < (unsigned)NIN);
            const _Float16* src = in + ((size_t)(((b * NIN + d) * NIN + h) * NIN + w)) * CIN + c0;
            _Float16* dst = &lds[hv * PADH];
            if constexpr (KC == 32) {
                f16x8 z = {};
#pragma unroll
                for (int i = 0; i < 4; ++i)
                    *(f16x8*)(dst + i * 8) = ok ? *(const f16x8*)(src + i * 8) : z;
            } else {
                f16x4 z = {};
#pragma unroll
                for (int i = 0; i < 4; ++i)
                    *(f16x4*)(dst + i * 4) = ok ? *(const f16x4*)(src + i * 4) : z;
            }
        }
        __syncthreads();

        // ---- 27 taps ----
#pragma unroll 1
        for (int kd = 0; kd < 3; ++kd) {
#pragma unroll
            for (int kh = 0; kh < 3; ++kh) {
#pragma unroll
                for (int kw = 0; kw < 3; ++kw) {
                    int tap = (kd * 3 + kh) * 3 + kw;
                    int hidx = row_off + (kd * HS + kh) * HS + kw;
                    size_t woff = (size_t)tap * COUT * CIN + c0;
                    if constexpr (KC == 32) {
                        f16x8 a = *(const f16x8*)(&lds[hidx * PADH + quad * 8]);
#pragma unroll
                        for (int nf = 0; nf < NF; ++nf) {
                            f16x8 bf = *(const f16x8*)(wlane + woff + (size_t)nf * 16 * CIN);
                            acc[nf] = __builtin_amdgcn_mfma_f32_16x16x32_f16(a, bf, acc[nf], 0, 0, 0);
                        }
                    } else {
                        f16x4 a = *(const f16x4*)(&lds[hidx * PADH + quad * 4]);
#pragma unroll
                        for (int nf = 0; nf < NF; ++nf) {
                            f16x4 bf = *(const f16x4*)(wlane + woff + (size_t)nf * 16 * CIN);
                            acc[nf] = __builtin_amdgcn_mfma_f32_16x16x16f16(a, bf, acc[nf], 0, 0, 0);
                        }
                    }
                }
            }
        }
    }

    // ---- epilogue: C/D layout col=lane&15 (cout), row=quad*4+r (voxel in slice)
    int odg = td * 4 + wv;
#pragma unroll
    for (int r = 0; r < 4; ++r) {
        int row = quad * 4 + r;
        int oh = th * 4 + (row >> 2);
        int ow = tw * 4 + (row & 3);
        size_t vox = ((size_t)((b * NOUT + odg) * NOUT + oh)) * NOUT + ow;
        float mv = mout[vox];
#pragma unroll
        for (int nf = 0; nf < NF; ++nf) {
            out[vox * COUT + nblk * NTILE + nf * 16 + m] = (_Float16)(acc[nf][r] * mv);
        }
    }
}

// ---------------- BN stats (fp16 in, fp32 accumulate) ----------------
template <int C>
__global__ __launch_bounds__(256) void bn_stats_kernel(const _Float16* __restrict__ x,
                                                       int nvox, float* __restrict__ stats) {
    if constexpr (C <= 256) {
        float s = 0.f, q = 0.f;
        long total = (long)nvox * C;
        long stride = (long)gridDim.x * 256;
        for (long i = (long)blockIdx.x * 256 + threadIdx.x; i < total; i += stride) {
            float v = (float)x[i];
            s += v;
            q += v * v;
        }
        __shared__ float ls[256], lq[256];
        ls[threadIdx.x] = s;
        lq[threadIdx.x] = q;
        __syncthreads();
        for (int st = 128; st >= C; st >>= 1) {
            if (threadIdx.x < st) {
                ls[threadIdx.x] += ls[threadIdx.x + st];
                lq[threadIdx.x] += lq[threadIdx.x + st];
            }
            __syncthreads();
        }
        if (threadIdx.x < C) {
            atomicAdd(&stats[threadIdx.x], ls[threadIdx.x]);
            atomicAdd(&stats[C + threadIdx.x], lq[threadIdx.x]);
        }
    } else {  // C == 512
        int c0 = threadIdx.x, c1 = threadIdx.x + 256;
        float s0 = 0.f, q0 = 0.f, s1 = 0.f, q1 = 0.f;
        for (int v = blockIdx.x; v < nvox; v += gridDim.x) {
            float a = (float)x[(size_t)v * C + c0];
            s0 += a; q0 += a * a;
            float b = (float)x[(size_t)v * C + c1];
            s1 += b; q1 += b * b;
        }
        atomicAdd(&stats[c0], s0);
        atomicAdd(&stats[C + c0], q0);
        atomicAdd(&stats[c1], s1);
        atomicAdd(&stats[C + c1], q1);
    }
}

// ---------------- BN apply + ELU + mask (fp16 in/out) ----------------
template <int C, int LOGC>
__global__ __launch_bounds__(256) void bn_apply_kernel(_Float16* __restrict__ x,
                                                       const float* __restrict__ m,
                                                       const float* __restrict__ stats,
                                                       const float* __restrict__ cnt,
                                                       const float* __restrict__ gamma,
                                                       const float* __restrict__ beta,
                                                       int nvox) {
    float cn = *cnt;
    long total = (long)nvox * C;
    long stride = (long)gridDim.x * blockDim.x;
    for (long i = (long)blockIdx.x * blockDim.x + threadIdx.x; i < total; i += stride) {
        int c = (int)(i & (C - 1));
        long v = i >> LOGC;
        float mean = stats[c] / cn;
        float var = stats[C + c] / cn - mean * mean;
        float xh = ((float)x[i] - mean) * rsqrtf(var + EPSV) * gamma[c] + beta[c];
        float e = xh > 0.f ? xh : expm1f(xh);
        x[i] = (_Float16)(e * m[v]);
    }
}

// ---------------- global masked mean pool ----------------
__global__ __launch_bounds__(256) void gpool_kernel(const _Float16* __restrict__ h,
                                                    float* __restrict__ pooled) {
    int b = blockIdx.x >> 4;
    int v0 = (blockIdx.x & 15) << 8;
    float s0 = 0.f, s1 = 0.f;
    for (int v = 0; v < 256; ++v) {
        const _Float16* p = h + ((size_t)(b * 4096 + v0 + v)) * 512;
        s0 += (float)p[threadIdx.x];
        s1 += (float)p[threadIdx.x + 256];
    }
    atomicAdd(&pooled[b * 512 + threadIdx.x], s0);
    atomicAdd(&pooled[b * 512 + threadIdx.x + 256], s1);
}

// ---------------- heads ----------------
__global__ __launch_bounds__(256) void head_kernel(const float* __restrict__ pooled,
                                                   const float* __restrict__ cntb,
                                                   const float* __restrict__ wm,
                                                   const float* __restrict__ bm,
                                                   const float* __restrict__ wv,
                                                   const float* __restrict__ bv,
                                                   float* __restrict__ out) {
    int t = blockIdx.x * 256 + threadIdx.x;  // 4096
    int which = t >> 11;
    int b = (t >> 9) & 3;
    int j = t & 511;
    const float* W = which ? wv : wm;
    float bias = which ? bv[j] : bm[j];
    const float* p = pooled + b * 512;
    float s = 0.f;
    for (int c = 0; c < 512; ++c) s = fmaf(p[c], W[c * 512 + j], s);
    out[t] = s / cntb[b] + bias;
}

// ---------------------------------------------------------------------------
extern "C" void kernel_launch(void* const* d_in, const int* in_sizes, int n_in,
                              void* d_out, int out_size, void* d_ws, size_t ws_size,
                              hipStream_t stream) {
    const float* x   = (const float*)d_in[0];
    const int* mask  = (const int*)d_in[1];
    const float* w1a = (const float*)d_in[2];
    const float* g1a = (const float*)d_in[3];
    const float* b1a = (const float*)d_in[4];
    const float* w1b = (const float*)d_in[5];
    const float* g1b = (const float*)d_in[6];
    const float* b1b = (const float*)d_in[7];
    const float* w2a = (const float*)d_in[8];
    const float* g2a = (const float*)d_in[9];
    const float* b2a = (const float*)d_in[10];
    const float* w2b = (const float*)d_in[11];
    const float* g2b = (const float*)d_in[12];
    const float* b2b = (const float*)d_in[13];
    const float* w3a = (const float*)d_in[14];
    const float* g3a = (const float*)d_in[15];
    const float* b3a = (const float*)d_in[16];
    const float* w3b = (const float*)d_in[17];
    const float* g3b = (const float*)d_in[18];
    const float* b3b = (const float*)d_in[19];
    const float* wm  = (const float*)d_in[20];
    const float* bm  = (const float*)d_in[21];
    const float* wv  = (const float*)d_in[22];
    const float* bv  = (const float*)d_in[23];
    float* out = (float*)d_out;

    char* ws = (char*)d_ws;
    // fp16 activation regions (32 MiB each), ping-pong:
    _Float16* A  = (_Float16*)(ws + 0);
    _Float16* Bb = (_Float16*)(ws + 33554432);
    // fp16 transposed weights:
    _Float16* w1bh = (_Float16*)(ws + 67108864);   //    13,824 B
    _Float16* w2ah = (_Float16*)(ws + 67122688);   //    55,296 B
    _Float16* w2bh = (_Float16*)(ws + 67177984);   //   221,184 B
    _Float16* w3ah = (_Float16*)(ws + 67399168);   // 1,769,472 B
    _Float16* w3bh = (_Float16*)(ws + 69168640);   //14,155,776 B
    float* m1 = (float*)(ws + 83324416);           // 4 MiB
    float* m2 = (float*)(ws + 87518720);           // 512 KiB
    float* m3 = (float*)(ws + 88043008);           // 64 KiB
    float* stats  = (float*)(ws + 88108544);       // 4 KiB
    float* counts = (float*)(ws + 88112640);       // 64 B
    float* pooled = (float*)(ws + 88112704);       // 8 KiB

    _Float16* h1a = A;
    _Float16* h1b = Bb;
    _Float16* h2a = A;
    _Float16* h2b = Bb;
    _Float16* h3a = A;
    _Float16* h3b = Bb;

    hipMemsetAsync(counts, 0, 64 + 8192, stream);

    // masks + counts
    pool0_kernel<<<4096, 256, 0, stream>>>(mask, m1);
    poolf_kernel<<<512, 256, 0, stream>>>(m1, m2, 32, 5);
    poolf_kernel<<<64, 256, 0, stream>>>(m2, m3, 16, 4);
    mask_count_kernel<<<1024, 256, 0, stream>>>(m1, 262144, 256, counts + 0, nullptr);
    mask_count_kernel<<<128, 256, 0, stream>>>(m2, 32768, 32, counts + 1, nullptr);
    mask_count_kernel<<<16, 256, 0, stream>>>(m3, 4096, 4, counts + 2, counts + 4);

    // weight transforms (fp32 [27][CIN][COUT] -> fp16 [27][COUT][CIN])
    wtrans_kernel<<<(6912 + 255) / 256, 256, 0, stream>>>(w1b, w1bh, 16, 16, 6912);
    wtrans_kernel<<<(27648 + 255) / 256, 256, 0, stream>>>(w2a, w2ah, 16, 64, 27648);
    wtrans_kernel<<<(110592 + 255) / 256, 256, 0, stream>>>(w2b, w2bh, 64, 64, 110592);
    wtrans_kernel<<<(884736 + 255) / 256, 256, 0, stream>>>(w3a, w3ah, 64, 512, 884736);
    wtrans_kernel<<<(7077888 + 255) / 256, 256, 0, stream>>>(w3b, w3bh, 512, 512, 7077888);

    // ---- block 1 ----
    conv1a_kernel<<<4096, 256, 0, stream>>>(x, mask, w1a, m1, h1a);
    hipMemsetAsync(stats, 0, 4096, stream);
    bn_stats_kernel<16><<<2048, 256, 0, stream>>>(h1a, 1048576, stats);
    bn_apply_kernel<16, 4><<<4096, 256, 0, stream>>>(h1a, m1, stats, counts + 0, g1a, b1a, 1048576);

    mfma_conv_kernel<16, 16, 16, 1, 64, 64><<<16384, 256, 0, stream>>>(h1a, w1bh, m1, h1b);
    hipMemsetAsync(stats, 0, 4096, stream);
    bn_stats_kernel<16><<<2048, 256, 0, stream>>>(h1b, 1048576, stats);
    bn_apply_kernel<16, 4><<<4096, 256, 0, stream>>>(h1b, m1, stats, counts + 0, g1b, b1b, 1048576);

    // ---- block 2 ----
    mfma_conv_kernel<16, 64, 64, 2, 64, 32><<<2048, 256, 0, stream>>>(h1b, w2ah, m2, h2a);
    hipMemsetAsync(stats, 0, 4096, stream);
    bn_stats_kernel<64><<<2048, 256, 0, stream>>>(h2a, 131072, stats);
    bn_apply_kernel<64, 6><<<2048, 256, 0, stream>>>(h2a, m2, stats, counts + 1, g2a, b2a, 131072);

    mfma_conv_kernel<64, 64, 64, 1, 32, 32><<<2048, 256, 0, stream>>>(h2a, w2bh, m2, h2b);
    hipMemsetAsync(stats, 0, 4096, stream);
    bn_stats_kernel<64><<<2048, 256, 0, stream>>>(h2b, 131072, stats);
    bn_apply_kernel<64, 6><<<2048, 256, 0, stream>>>(h2b, m2, stats, counts + 1, g2b, b2b, 131072);

    // ---- block 3 ----
    mfma_conv_kernel<64, 512, 128, 2, 32, 16><<<1024, 256, 0, stream>>>(h2b, w3ah, m3, h3a);
    hipMemsetAsync(stats, 0, 4096, stream);
    bn_stats_kernel<512><<<1024, 256, 0, stream>>>(h3a, 16384, stats);
    bn_apply_kernel<512, 9><<<2048, 256, 0, stream>>>(h3a, m3, stats, counts + 2, g3a, b3a, 16384);

    mfma_conv_kernel<512, 512, 128, 1, 16, 16><<<1024, 256, 0, stream>>>(h3a, w3bh, m3, h3b);
    hipMemsetAsync(stats, 0, 4096, stream);
    bn_stats_kernel<512><<<1024, 256, 0, stream>>>(h3b, 16384, stats);
    bn_apply_kernel<512, 9><<<2048, 256, 0, stream>>>(h3b, m3, stats, counts + 2, g3b, b3b, 16384);

    // ---- pool + heads ----
    gpool_kernel<<<64, 256, 0, stream>>>(h3b, pooled);
    head_kernel<<<16, 256, 0, stream>>>(pooled, counts + 4, wm, bm, wv, bv, out);
}

// Round 3
// 1270.961 us; speedup vs baseline: 5.9813x; 2.1662x over previous
//
#include <hip/hip_runtime.h>
#include <cstddef>

// ---------------------------------------------------------------------------
// Encoder, round 3: unified MFMA implicit-GEMM conv template.
//  - B (weights) tile staged to LDS via global_load_lds(16B), double-buffered
//    across the 27 taps (stage t+1 while MFMAs run on t).
//  - A (activations) halo in LDS at 64B/voxel pitch (even bank spread).
//  - wave tile up to M64xN64 (16 MFMAs per K-step of 32).
//  - BN: vectorized f16x8 stats + coef precompute + vectorized apply.
// ---------------------------------------------------------------------------

#define EPSV 1e-5f

typedef _Float16 f16x4 __attribute__((ext_vector_type(4)));
typedef _Float16 f16x8 __attribute__((ext_vector_type(8)));
typedef float f32x4 __attribute__((ext_vector_type(4)));

template <int KC> struct FragSel;
template <> struct FragSel<32> { using T = f16x8; };
template <> struct FragSel<16> { using T = f16x4; };

__device__ __forceinline__ f32x4 mfma16(f16x8 a, f16x8 b, f32x4 c) {
    return __builtin_amdgcn_mfma_f32_16x16x32_f16(a, b, c, 0, 0, 0);
}
__device__ __forceinline__ f32x4 mfma16(f16x4 a, f16x4 b, f32x4 c) {
    return __builtin_amdgcn_mfma_f32_16x16x16f16(a, b, c, 0, 0, 0);
}

// async global->LDS, 16B per lane; LDS dest = wave-uniform base + lane*16
__device__ __forceinline__ void gld16(const void* g, void* l) {
    __builtin_amdgcn_global_load_lds(
        (const __attribute__((address_space(1))) unsigned int*)g,
        (__attribute__((address_space(3))) unsigned int*)l, 16, 0, 0);
}

// ---------------- mask pooling ----------------
__global__ __launch_bounds__(256) void pool0_kernel(const int* __restrict__ mask,
                                                    float* __restrict__ mout) {
    int voxel = blockIdx.x * 256 + threadIdx.x;          // 4 * 64^3
    int wo = voxel & 63, ho = (voxel >> 6) & 63, dd = (voxel >> 12) & 63, b = voxel >> 18;
    int any = 0;
#pragma unroll
    for (int dz = 0; dz < 2; ++dz)
#pragma unroll
        for (int hy = 0; hy < 2; ++hy)
#pragma unroll
            for (int wx = 0; wx < 2; ++wx) {
                size_t idx = ((size_t)((b * 128 + 2 * dd + dz) * 128 + 2 * ho + hy)) * 128
                             + 2 * wo + wx;
                any |= mask[idx];
            }
    mout[voxel] = any ? 1.f : 0.f;
}

__global__ __launch_bounds__(256) void poolf_kernel(const float* __restrict__ min_,
                                                    float* __restrict__ mout,
                                                    int Nout, int lnout) {
    int voxel = blockIdx.x * 256 + threadIdx.x;
    int Nin = Nout * 2;
    int wo = voxel & (Nout - 1);
    int ho = (voxel >> lnout) & (Nout - 1);
    int dd = (voxel >> (2 * lnout)) & (Nout - 1);
    int b = voxel >> (3 * lnout);
    float mx = 0.f;
#pragma unroll
    for (int dz = 0; dz < 2; ++dz)
#pragma unroll
        for (int hy = 0; hy < 2; ++hy)
#pragma unroll
            for (int wx = 0; wx < 2; ++wx) {
                size_t idx = ((size_t)((b * Nin + 2 * dd + dz) * Nin + 2 * ho + hy)) * Nin
                             + 2 * wo + wx;
                mx = fmaxf(mx, min_[idx]);
            }
    mout[voxel] = mx;
}

// ---------------- mask counts ----------------
__global__ __launch_bounds__(256) void mask_count_kernel(const float* __restrict__ m,
                                                         int nper, int blocks_per_batch,
                                                         float* __restrict__ cnt_total,
                                                         float* __restrict__ cnt_batch) {
    int batch = blockIdx.x / blocks_per_batch;
    int off = (blockIdx.x % blocks_per_batch) * 1024;
    float s = 0.f;
    for (int i = threadIdx.x; i < 1024; i += 256)
        s += m[(size_t)batch * nper + off + i];
    __shared__ float red[256];
    red[threadIdx.x] = s;
    __syncthreads();
    for (int st = 128; st > 0; st >>= 1) {
        if (threadIdx.x < st) red[threadIdx.x] += red[threadIdx.x + st];
        __syncthreads();
    }
    if (threadIdx.x == 0) {
        atomicAdd(cnt_total, red[0]);
        if (cnt_batch) atomicAdd(&cnt_batch[batch], red[0]);
    }
}

// ---------------- weight transform: [27][CIN][COUT] f32 -> [27][COUT][CIN] f16
__global__ __launch_bounds__(256) void wtrans_kernel(const float* __restrict__ w,
                                                     _Float16* __restrict__ o,
                                                     int CIN, int COUT, int total) {
    int i = blockIdx.x * 256 + threadIdx.x;
    if (i >= total) return;
    int co = i % COUT;
    int rest = i / COUT;
    int ci = rest % CIN;
    int t = rest / CIN;
    o[((size_t)(t * COUT + co)) * CIN + ci] = (_Float16)w[i];
}

// ---------------- conv1a: Cin=1, Cout=16, stride 2 (VALU) ----------
__global__ __launch_bounds__(256) void conv1a_kernel(const float* __restrict__ x,
                                                     const int* __restrict__ mask,
                                                     const float* __restrict__ w,
                                                     const float* __restrict__ m1,
                                                     _Float16* __restrict__ out) {
    int voxel = blockIdx.x * 256 + threadIdx.x;  // 4 * 64^3
    int wo = voxel & 63, ho = (voxel >> 6) & 63, dd = (voxel >> 12) & 63, b = voxel >> 18;
    float acc[16];
#pragma unroll
    for (int i = 0; i < 16; ++i) acc[i] = 0.f;
    for (int kd = 0; kd < 3; ++kd) {
        int id = 2 * dd + kd - 1;
        if ((unsigned)id >= 128u) continue;
        for (int kh = 0; kh < 3; ++kh) {
            int ih = 2 * ho + kh - 1;
            if ((unsigned)ih >= 128u) continue;
            for (int kw = 0; kw < 3; ++kw) {
                int iw = 2 * wo + kw - 1;
                if ((unsigned)iw >= 128u) continue;
                size_t idx = ((size_t)((b * 128 + id) * 128 + ih)) * 128 + iw;
                float xv = x[idx] * (float)mask[idx];
                const float* wp = w + ((kd * 3 + kh) * 3 + kw) * 16;
#pragma unroll
                for (int co = 0; co < 16; ++co) acc[co] = fmaf(xv, wp[co], acc[co]);
            }
        }
    }
    float m = m1[voxel];
    _Float16* op = out + (size_t)voxel * 16;
#pragma unroll
    for (int co = 0; co < 16; ++co) op[co] = (_Float16)(acc[co] * m);
}

// ---------------- unified MFMA implicit-GEMM conv ----------------
// Block: 256 threads = 4 waves (WM in M x 4/WM in N). Output tile:
// M = TW*TH*TD voxels x NTILE couts. Halo in LDS (KC channels, 64B/32B pitch),
// weights double-buffered per tap via global_load_lds.
template <int CIN, int COUT, int NTILE, int STRIDE, int NIN, int NOUT,
          int TW, int LTW, int TH, int LTH, int TD, int WM>
__global__ __launch_bounds__(256, 2) void conv_mfma(const _Float16* __restrict__ in,
                                                    const _Float16* __restrict__ wt,
                                                    const float* __restrict__ mout,
                                                    _Float16* __restrict__ out,
                                                    const _Float16* __restrict__ zbuf) {
    constexpr int M = TW * TH * TD;
    constexpr int KC = (CIN >= 32) ? 32 : 16;
    constexpr int HW_ = (TW - 1) * STRIDE + 3;
    constexpr int HH_ = (TH - 1) * STRIDE + 3;
    constexpr int HD_ = (TD - 1) * STRIDE + 3;
    constexpr int HV = HW_ * HH_ * HD_;
    constexpr int LPV = (KC * 2) / 16;        // lanes per voxel/row (4 or 2)
    constexpr int VPI = 64 / LPV;             // voxels per stage inst (16 or 32)
    constexpr int NIH = (HV + VPI - 1) / VPI;
    constexpr int HVP = NIH * VPI;
    constexpr int WN = 4 / WM;
    constexpr int WMT = M / WM;
    constexpr int WNT = NTILE / WN;
    constexpr int NAF = WMT / 16;
    constexpr int NBF = WNT / 16;
    constexpr int NBLK = COUT / NTILE;
    constexpr int NTW = NOUT / TW, NTH = NOUT / TH, NTD = NOUT / TD;
    constexpr int NUMM = 4 * NTW * NTH * NTD;
    constexpr int BI = (NTILE * KC * 2 + 1023) / 1024;  // B stage insts per tap

    using Frag = typename FragSel<KC>::T;

    __shared__ _Float16 halo[HVP * KC];
    __shared__ _Float16 bbuf[2 * NTILE * KC];

    int bid = blockIdx.x;
    int nblk = (NBLK > 1) ? bid / NUMM : 0;
    int mblk = (NBLK > 1) ? bid % NUMM : bid;
    int tw = mblk % NTW;
    int th = (mblk / NTW) % NTH;
    int td = (mblk / (NTW * NTH)) % NTD;
    int b = mblk / (NTW * NTH * NTD);
    int d0 = td * TD * STRIDE - 1, h0 = th * TH * STRIDE - 1, w0 = tw * TW * STRIDE - 1;

    int tid = threadIdx.x;
    int wv = tid >> 6, lane = tid & 63, m16 = lane & 15, quad = lane >> 4;
    int wm_ = wv % WM, wn_ = wv / WM;
    int quadA = quad * (KC / 4);

    int abase[NAF];
#pragma unroll
    for (int r = 0; r < NAF; ++r) {
        int vloc = wm_ * WMT + r * 16 + m16;
        int vw = vloc & (TW - 1), vh = (vloc >> LTW) & (TH - 1), vd = vloc >> (LTW + LTH);
        abase[r] = ((vd * STRIDE) * HH_ + vh * STRIDE) * HW_ + vw * STRIDE;
    }
    int bofs = (wn_ * WNT + m16) * KC + quadA;

    f32x4 acc[NAF][NBF];
#pragma unroll
    for (int r = 0; r < NAF; ++r)
#pragma unroll
        for (int f = 0; f < NBF; ++f) acc[r][f] = (f32x4){0.f, 0.f, 0.f, 0.f};

    auto stage_halo = [&](int c0) {
        for (int i = wv; i < NIH; i += 4) {
            int sl = lane / LPV, ck = lane % LPV;
            int hv = i * VPI + sl;
            int hw = hv % HW_;
            int t2 = hv / HW_;
            int hh = t2 % HH_;
            int hd = t2 / HH_;
            int d = d0 + hd, h = h0 + hh, w = w0 + hw;
            bool ok = (hv < HV) && ((unsigned)d < (unsigned)NIN) &&
                      ((unsigned)h < (unsigned)NIN) && ((unsigned)w < (unsigned)NIN);
            const _Float16* g =
                ok ? in + ((size_t)(((b * NIN + d) * NIN + h) * NIN + w)) * CIN + c0 + ck * 8
                   : zbuf;
            gld16(g, &halo[i * VPI * KC]);
        }
    };

    auto stage_B = [&](int tap, int buf, int c0) {
        const _Float16* wb = wt + (size_t)tap * COUT * CIN + (size_t)nblk * NTILE * CIN + c0;
        for (int i = wv; i < BI; i += 4) {
            int row = i * (1024 / (KC * 2)) + lane / LPV;
            int ck = lane % LPV;
            if (row < NTILE)
                gld16(wb + (size_t)row * CIN + ck * 8,
                      &bbuf[buf * NTILE * KC + i * (1024 / (KC * 2)) * KC]);
        }
    };

    for (int c0 = 0; c0 < CIN; c0 += KC) {
        __syncthreads();   // all reads of previous halo/B done
        stage_halo(c0);
        stage_B(0, 0, c0);
        for (int t = 0; t < 27; ++t) {
            __syncthreads();   // staged data for tap t visible
            if (t < 26) stage_B(t + 1, (t + 1) & 1, c0);
            int tapv = ((t / 9) * HH_ + ((t % 9) / 3)) * HW_ + (t % 3);
            Frag a[NAF], bb[NBF];
#pragma unroll
            for (int r = 0; r < NAF; ++r)
                a[r] = *(const Frag*)&halo[(abase[r] + tapv) * KC + quadA];
            const _Float16* bp = &bbuf[(t & 1) * NTILE * KC];
#pragma unroll
            for (int f = 0; f < NBF; ++f) bb[f] = *(const Frag*)&bp[bofs + f * 16 * KC];
#pragma unroll
            for (int r = 0; r < NAF; ++r)
#pragma unroll
                for (int f = 0; f < NBF; ++f) acc[r][f] = mfma16(a[r], bb[f], acc[r][f]);
        }
    }

    // epilogue: C/D col = m16 (cout), row = quad*4 + j (voxel within frag)
    int n0 = nblk * NTILE + wn_ * WNT + m16;
#pragma unroll
    for (int r = 0; r < NAF; ++r) {
#pragma unroll
        for (int j = 0; j < 4; ++j) {
            int vloc = wm_ * WMT + r * 16 + quad * 4 + j;
            int vw = vloc & (TW - 1), vh = (vloc >> LTW) & (TH - 1), vd = vloc >> (LTW + LTH);
            int od = td * TD + vd, oh = th * TH + vh, ow = tw * TW + vw;
            size_t gvox = ((size_t)((b * NOUT + od) * NOUT + oh)) * NOUT + ow;
            float mv = mout[gvox];
            _Float16* op = out + gvox * COUT + n0;
#pragma unroll
            for (int f = 0; f < NBF; ++f) op[f * 16] = (_Float16)(acc[r][f][j] * mv);
        }
    }
}

// ---------------- BN stats: vectorized f16x8, per-channel sum/sumsq ---------
template <int C>
__global__ __launch_bounds__(256) void bn_stats_v(const _Float16* __restrict__ x,
                                                  long n, float* __restrict__ stats) {
    constexpr int G = C / 8;
    float s[8], q[8];
#pragma unroll
    for (int k = 0; k < 8; ++k) { s[k] = 0.f; q[k] = 0.f; }
    long stride = (long)gridDim.x * 2048;
    for (long i = ((long)blockIdx.x * 256 + threadIdx.x) * 8; i < n; i += stride) {
        f16x8 v = *(const f16x8*)(x + i);
#pragma unroll
        for (int k = 0; k < 8; ++k) {
            float f = (float)v[k];
            s[k] += f;
            q[k] += f * f;
        }
    }
    __shared__ float red[256 * 16];
#pragma unroll
    for (int k = 0; k < 8; ++k) {
        red[threadIdx.x * 16 + k] = s[k];
        red[threadIdx.x * 16 + 8 + k] = q[k];
    }
    __syncthreads();
    for (int st = 128; st >= G; st >>= 1) {
        if (threadIdx.x < st) {
#pragma unroll
            for (int k = 0; k < 16; ++k)
                red[threadIdx.x * 16 + k] += red[(threadIdx.x + st) * 16 + k];
        }
        __syncthreads();
    }
    if (threadIdx.x < G) {
        int cb = threadIdx.x * 8;
#pragma unroll
        for (int k = 0; k < 8; ++k) {
            atomicAdd(&stats[cb + k], red[threadIdx.x * 16 + k]);
            atomicAdd(&stats[C + cb + k], red[threadIdx.x * 16 + 8 + k]);
        }
    }
}

// ---------------- BN coef: scale/shift from stats ----------------
__global__ void bn_coef_kernel(const float* __restrict__ stats, const float* __restrict__ cnt,
                               const float* __restrict__ gamma, const float* __restrict__ beta,
                               float* __restrict__ coef, int C) {
    int c = threadIdx.x;
    if (c >= C) return;
    float cn = *cnt;
    float mean = stats[c] / cn;
    float var = stats[C + c] / cn - mean * mean;
    float sc = rsqrtf(var + EPSV) * gamma[c];
    coef[c] = sc;
    coef[C + c] = beta[c] - mean * sc;
}

// ---------------- BN apply + ELU + mask (vectorized) ----------------
template <int C, int LOGC>
__global__ __launch_bounds__(256) void bn_apply_v(_Float16* __restrict__ x,
                                                  const float* __restrict__ m,
                                                  const float* __restrict__ coef, long n) {
    long stride = (long)gridDim.x * 2048;
    for (long i8 = ((long)blockIdx.x * 256 + threadIdx.x) * 8; i8 < n; i8 += stride) {
        int c = (int)(i8 & (C - 1));
        long v = i8 >> LOGC;
        f16x8 xv = *(const f16x8*)(x + i8);
        float mv = m[v];
        f16x8 o;
#pragma unroll
        for (int k = 0; k < 8; ++k) {
            float xh = (float)xv[k] * coef[c + k] + coef[C + c + k];
            float e = xh > 0.f ? xh : expm1f(xh);
            o[k] = (_Float16)(e * mv);
        }
        *(f16x8*)(x + i8) = o;
    }
}

// ---------------- global masked mean pool (sums) ----------------
__global__ __launch_bounds__(256) void gpool_kernel(const _Float16* __restrict__ h,
                                                    float* __restrict__ pooled) {
    int b = blockIdx.x >> 3, seg = blockIdx.x & 7;  // 8 segments of 512 voxels
    int ch = (threadIdx.x & 63) * 8;
    int v0 = threadIdx.x >> 6;
    float s[8];
#pragma unroll
    for (int k = 0; k < 8; ++k) s[k] = 0.f;
    for (int v = v0; v < 512; v += 4) {
        const _Float16* p = h + ((size_t)(b * 4096 + seg * 512 + v)) * 512 + ch;
        f16x8 xv = *(const f16x8*)p;
#pragma unroll
        for (int k = 0; k < 8; ++k) s[k] += (float)xv[k];
    }
#pragma unroll
    for (int k = 0; k < 8; ++k) atomicAdd(&pooled[b * 512 + ch + k], s[k]);
}

// ---------------- heads ----------------
__global__ __launch_bounds__(256) void head_kernel(const float* __restrict__ pooled,
                                                   const float* __restrict__ cntb,
                                                   const float* __restrict__ wm,
                                                   const float* __restrict__ bm,
                                                   const float* __restrict__ wv,
                                                   const float* __restrict__ bv,
                                                   float* __restrict__ out) {
    int t = blockIdx.x * 256 + threadIdx.x;  // 4096
    int which = t >> 11;
    int b = (t >> 9) & 3;
    int j = t & 511;
    const float* W = which ? wv : wm;
    float bias = which ? bv[j] : bm[j];
    const float* p = pooled + b * 512;
    float s = 0.f;
    for (int c = 0; c < 512; ++c) s = fmaf(p[c], W[c * 512 + j], s);
    out[t] = s / cntb[b] + bias;
}

// ---------------------------------------------------------------------------
extern "C" void kernel_launch(void* const* d_in, const int* in_sizes, int n_in,
                              void* d_out, int out_size, void* d_ws, size_t ws_size,
                              hipStream_t stream) {
    const float* x   = (const float*)d_in[0];
    const int* mask  = (const int*)d_in[1];
    const float* w1a = (const float*)d_in[2];
    const float* g1a = (const float*)d_in[3];
    const float* b1a = (const float*)d_in[4];
    const float* w1b = (const float*)d_in[5];
    const float* g1b = (const float*)d_in[6];
    const float* b1b = (const float*)d_in[7];
    const float* w2a = (const float*)d_in[8];
    const float* g2a = (const float*)d_in[9];
    const float* b2a = (const float*)d_in[10];
    const float* w2b = (const float*)d_in[11];
    const float* g2b = (const float*)d_in[12];
    const float* b2b = (const float*)d_in[13];
    const float* w3a = (const float*)d_in[14];
    const float* g3a = (const float*)d_in[15];
    const float* b3a = (const float*)d_in[16];
    const float* w3b = (const float*)d_in[17];
    const float* g3b = (const float*)d_in[18];
    const float* b3b = (const float*)d_in[19];
    const float* wm  = (const float*)d_in[20];
    const float* bm  = (const float*)d_in[21];
    const float* wv  = (const float*)d_in[22];
    const float* bv  = (const float*)d_in[23];
    float* out = (float*)d_out;

    char* ws = (char*)d_ws;
    _Float16* A  = (_Float16*)(ws + 0);            // 32 MiB activations ping
    _Float16* Bb = (_Float16*)(ws + 33554432);     // 32 MiB activations pong
    _Float16* w1bh = (_Float16*)(ws + 67108864);   // 13,824 B (+pad for over-read)
    _Float16* w2ah = (_Float16*)(ws + 67125248);   // 55,296 B
    _Float16* w2bh = (_Float16*)(ws + 67182592);   // 221,184 B
    _Float16* w3ah = (_Float16*)(ws + 67403776);   // 1,769,472 B
    _Float16* w3bh = (_Float16*)(ws + 69173248);   // 14,155,776 B
    float* m1 = (float*)(ws + 83329024);           // 4 MiB
    float* m2 = (float*)(ws + 87523328);           // 512 KiB
    float* m3 = (float*)(ws + 88047616);           // 64 KiB
    float* stats  = (float*)(ws + 88113152);       // 4 KiB
    float* coef   = (float*)(ws + 88117248);       // 4 KiB
    float* counts = (float*)(ws + 88121344);       // 64 B
    float* pooled = (float*)(ws + 88121408);       // 8 KiB
    _Float16* zbuf = (_Float16*)(ws + 88129600);   // 256 B zeros

    _Float16* h1a = A;
    _Float16* h1b = Bb;
    _Float16* h2a = A;
    _Float16* h2b = Bb;
    _Float16* h3a = A;
    _Float16* h3b = Bb;

    hipMemsetAsync(counts, 0, 64 + 8192, stream);   // counts + pooled
    hipMemsetAsync(zbuf, 0, 256, stream);

    // masks + counts
    pool0_kernel<<<4096, 256, 0, stream>>>(mask, m1);
    poolf_kernel<<<512, 256, 0, stream>>>(m1, m2, 32, 5);
    poolf_kernel<<<64, 256, 0, stream>>>(m2, m3, 16, 4);
    mask_count_kernel<<<1024, 256, 0, stream>>>(m1, 262144, 256, counts + 0, nullptr);
    mask_count_kernel<<<128, 256, 0, stream>>>(m2, 32768, 32, counts + 1, nullptr);
    mask_count_kernel<<<16, 256, 0, stream>>>(m3, 4096, 4, counts + 2, counts + 4);

    // weight transforms (fp32 [27][CIN][COUT] -> fp16 [27][COUT][CIN])
    wtrans_kernel<<<(6912 + 255) / 256, 256, 0, stream>>>(w1b, w1bh, 16, 16, 6912);
    wtrans_kernel<<<(27648 + 255) / 256, 256, 0, stream>>>(w2a, w2ah, 16, 64, 27648);
    wtrans_kernel<<<(110592 + 255) / 256, 256, 0, stream>>>(w2b, w2bh, 64, 64, 110592);
    wtrans_kernel<<<(884736 + 255) / 256, 256, 0, stream>>>(w3a, w3ah, 64, 512, 884736);
    wtrans_kernel<<<(7077888 + 255) / 256, 256, 0, stream>>>(w3b, w3bh, 512, 512, 7077888);

    // ---- block 1 ----
    conv1a_kernel<<<4096, 256, 0, stream>>>(x, mask, w1a, m1, h1a);
    hipMemsetAsync(stats, 0, 4096, stream);
    bn_stats_v<16><<<512, 256, 0, stream>>>(h1a, 16777216L, stats);
    bn_coef_kernel<<<1, 512, 0, stream>>>(stats, counts + 0, g1a, b1a, coef, 16);
    bn_apply_v<16, 4><<<2048, 256, 0, stream>>>(h1a, m1, coef, 16777216L);

    conv_mfma<16, 16, 16, 1, 64, 64, 8, 3, 4, 2, 4, 4>
        <<<8192, 256, 0, stream>>>(h1a, w1bh, m1, h1b, zbuf);
    hipMemsetAsync(stats, 0, 4096, stream);
    bn_stats_v<16><<<512, 256, 0, stream>>>(h1b, 16777216L, stats);
    bn_coef_kernel<<<1, 512, 0, stream>>>(stats, counts + 0, g1b, b1b, coef, 16);
    bn_apply_v<16, 4><<<2048, 256, 0, stream>>>(h1b, m1, coef, 16777216L);

    // ---- block 2 ----
    conv_mfma<16, 64, 64, 2, 64, 32, 4, 2, 4, 2, 4, 2>
        <<<2048, 256, 0, stream>>>(h1b, w2ah, m2, h2a, zbuf);
    hipMemsetAsync(stats, 0, 4096, stream);
    bn_stats_v<64><<<256, 256, 0, stream>>>(h2a, 8388608L, stats);
    bn_coef_kernel<<<1, 512, 0, stream>>>(stats, counts + 1, g2a, b2a, coef, 64);
    bn_apply_v<64, 6><<<1024, 256, 0, stream>>>(h2a, m2, coef, 8388608L);

    conv_mfma<64, 64, 64, 1, 32, 32, 8, 3, 4, 2, 4, 2>
        <<<1024, 256, 0, stream>>>(h2a, w2bh, m2, h2b, zbuf);
    hipMemsetAsync(stats, 0, 4096, stream);
    bn_stats_v<64><<<256, 256, 0, stream>>>(h2b, 8388608L, stats);
    bn_coef_kernel<<<1, 512, 0, stream>>>(stats, counts + 1, g2b, b2b, coef, 64);
    bn_apply_v<64, 6><<<1024, 256, 0, stream>>>(h2b, m2, coef, 8388608L);

    // ---- block 3 ----
    conv_mfma<64, 512, 128, 2, 32, 16, 4, 2, 4, 2, 4, 2>
        <<<1024, 256, 0, stream>>>(h2b, w3ah, m3, h3a, zbuf);
    hipMemsetAsync(stats, 0, 4096, stream);
    bn_stats_v<512><<<128, 256, 0, stream>>>(h3a, 8388608L, stats);
    bn_coef_kernel<<<1, 512, 0, stream>>>(stats, counts + 2, g3a, b3a, coef, 512);
    bn_apply_v<512, 9><<<512, 256, 0, stream>>>(h3a, m3, coef, 8388608L);

    conv_mfma<512, 512, 128, 1, 16, 16, 8, 3, 4, 2, 4, 2>
        <<<512, 256, 0, stream>>>(h3a, w3bh, m3, h3b, zbuf);
    hipMemsetAsync(stats, 0, 4096, stream);
    bn_stats_v<512><<<128, 256, 0, stream>>>(h3b, 8388608L, stats);
    bn_coef_kernel<<<1, 512, 0, stream>>>(stats, counts + 2, g3b, b3b, coef, 512);
    bn_apply_v<512, 9><<<512, 256, 0, stream>>>(h3b, m3, coef, 8388608L);

    // ---- pool + heads ----
    gpool_kernel<<<32, 256, 0, stream>>>(h3b, pooled);
    head_kernel<<<16, 256, 0, stream>>>(pooled, counts + 4, wm, bm, wv, bv, out);
}